// Round 17
// baseline (340.723 us; speedup 1.0000x reference)
//
#include <hip/hip_runtime.h>
#include <hip/hip_bf16.h>

#define NN 100000
#define NE 1600000
#define DF 512
#define NIDX 10000

#define NBKT 512
#define BKT_W 196                 // ceil(100000/512); 512*196 = 100352 >= NN
#define EDGES_PER_BKT_BLK 3125    // NE / 512 exactly
#define GEMM1_NB 782              // (NN+127)/128
#define GEMM1A 391                // first-half blocks
#define GEMM1B (GEMM1_NB - GEMM1A)

typedef __attribute__((ext_vector_type(8))) short short8v;
typedef __attribute__((ext_vector_type(4))) float float4v;

__device__ __forceinline__ float eluf(float x) { return x > 0.f ? x : expm1f(x); }
__device__ __forceinline__ float lrelu(float x) { return x > 0.f ? x : 0.2f * x; }
__device__ __forceinline__ ushort f2bf(float f) {
  __hip_bfloat16 b = __float2bfloat16(f);
  return *(ushort*)&b;
}

// global_load_lds: 16B per lane, dest = uniform LDS base + lane*16 (CK cast pattern)
__device__ __forceinline__ void glds16(const void* gsrc, void* ldst) {
  __builtin_amdgcn_global_load_lds(
      (const __attribute__((address_space(1))) uint32_t*)(uintptr_t)gsrc,
      (__attribute__((address_space(3))) uint32_t*)(uintptr_t)ldst, 16, 0, 0);
}

// ---------------- prep_w (blocks 0..127) + edge histogram (blocks 128..639) ----------------
__global__ __launch_bounds__(256) void prep_w_hist(const float* __restrict__ W1,
                                                   ushort* __restrict__ Wt_hi, ushort* __restrict__ Wt_lo,
                                                   const int2* __restrict__ edges, int* __restrict__ bkt_cnt) {
  const int tid = threadIdx.x;
  if (blockIdx.x >= 128) {
    __shared__ int h[NBKT];
    h[tid] = 0; h[tid + 256] = 0;
    __syncthreads();
    const int b = blockIdx.x - 128;
    const int i0 = b * EDGES_PER_BKT_BLK;
    const int i1 = min(i0 + EDGES_PER_BKT_BLK, NE);
    for (int i = i0 + tid; i < i1; i += 256) atomicAdd(&h[edges[i].x / BKT_W], 1);
    __syncthreads();
    if (h[tid]) atomicAdd(&bkt_cnt[tid], h[tid]);
    if (h[tid + 256]) atomicAdd(&bkt_cnt[tid + 256], h[tid + 256]);
    return;
  }
  int t = blockIdx.x * 256 + tid;          // t < 32768 = DF*64
  int k = t >> 6, n = t & 63;
  float w = W1[t];
  ushort hi = f2bf(w);
  __hip_bfloat16 hb = *(__hip_bfloat16*)&hi;
  ushort lo = f2bf(w - __bfloat162float(hb));
  Wt_hi[(size_t)n * DF + k] = hi;
  Wt_lo[(size_t)n * DF + k] = lo;
}

// ---------------- layer-1 GEMM half + co-scheduled CSR tail ----------------
#define BSTRIDE 40
template<int TAIL>
__global__ __launch_bounds__(256) void gemm1_mix(const float* __restrict__ x,
                                                 const ushort* __restrict__ Wt_hi, const ushort* __restrict__ Wt_lo,
                                                 const float* __restrict__ a1s, const float* __restrict__ a1d,
                                                 ushort* __restrict__ h1b, float* __restrict__ s_src,
                                                 float* __restrict__ s_dst,
                                                 int gemm_cnt, int gemm_off,
                                                 const int2* __restrict__ edges, int* __restrict__ bkt_cursor,
                                                 uint* __restrict__ pairs,
                                                 const int* __restrict__ bkt_base, int* __restrict__ row_off,
                                                 int* __restrict__ ssrc) {
  __shared__ __align__(16) char smem[53248];
  const int tid = threadIdx.x;

  if (blockIdx.x >= (unsigned)gemm_cnt) {
    const int tb = blockIdx.x - gemm_cnt;
    if (TAIL == 0) {
      // ---- bucket reorder ----
      int* h = (int*)smem;
      int* lbase = h + NBKT;
      int* cur = lbase + NBKT;
      h[tid] = 0; h[tid + 256] = 0;
      __syncthreads();
      const int i0 = tb * EDGES_PER_BKT_BLK;
      const int i1 = min(i0 + EDGES_PER_BKT_BLK, NE);
      for (int i = i0 + tid; i < i1; i += 256) atomicAdd(&h[edges[i].x / BKT_W], 1);
      __syncthreads();
#pragma unroll
      for (int q = 0; q < 2; ++q) {
        int b = tid + q * 256;
        int c = h[b];
        lbase[b] = c ? atomicAdd(&bkt_cursor[b], c) : 0;
        cur[b] = 0;
      }
      __syncthreads();
      for (int i = i0 + tid; i < i1; i += 256) {
        int2 e = edges[i];
        int bk = e.x / BKT_W;
        int r = atomicAdd(&cur[bk], 1);
        pairs[lbase[bk] + r] = ((uint)(e.x - bk * BKT_W) << 24) | (uint)e.y;
      }
    } else {
      // ---- bucket build ----
      int* hist = (int*)smem;
      int* ts = hist + 256;
      int* cur = ts + 256;
      const int d0 = tb * BKT_W;
      if (d0 >= NN) return;
      const int nd = min(BKT_W, NN - d0);
      const int beg = bkt_base[tb], end = bkt_base[tb + 1];
      hist[tid] = 0;
      __syncthreads();
      for (int i = beg + tid; i < end; i += 256) atomicAdd(&hist[pairs[i] >> 24], 1);
      __syncthreads();
      int v = hist[tid];
      ts[tid] = v;
      __syncthreads();
      for (int off = 1; off < 256; off <<= 1) {
        int t2 = (tid >= off) ? ts[tid - off] : 0;
        __syncthreads();
        ts[tid] += t2;
        __syncthreads();
      }
      int excl = ts[tid] - v;
      if (tid < nd) row_off[d0 + tid] = beg + excl;
      cur[tid] = beg + excl;
      __syncthreads();
      for (int i = beg + tid; i < end; i += 256) {
        uint p = pairs[i];
        int pos = atomicAdd(&cur[p >> 24], 1);
        ssrc[pos] = (int)(p & 0xFFFFFFu);
      }
    }
    return;
  }

  // ---- GEMM path ----
  float* Abuf[2];
  Abuf[0] = (float*)smem;
  Abuf[1] = (float*)(smem + 16384);
  ushort* Bhi[2]; ushort* Blo[2];
  Bhi[0] = (ushort*)(smem + 32768);
  Blo[0] = Bhi[0] + 64 * BSTRIDE;
  Bhi[1] = Blo[0] + 64 * BSTRIDE;
  Blo[1] = Bhi[1] + 64 * BSTRIDE;
  float* Cs = (float*)smem;                    // epilogue alias, stride 65

  const int mb = (gemm_off + blockIdx.x) * 128;
  const int wave = tid >> 6, l = tid & 63;
  const int wm = wave * 32;
  const int lm = l & 15, kq = l >> 4, kg = kq * 8;

  float4v acc[2][4];
#pragma unroll
  for (int i = 0; i < 2; ++i)
#pragma unroll
    for (int j = 0; j < 4; ++j) acc[i][j] = (float4v){0.f, 0.f, 0.f, 0.f};

  size_t asrc[4];
#pragma unroll
  for (int i = 0; i < 4; ++i) {
    int g = mb + wm + 8 * i + (l >> 3);
    if (g > NN - 1) g = NN - 1;
    asrc[i] = (size_t)g * DF + (l & 7) * 4;
  }
  const int bn = tid & 63, bk = (tid >> 6) * 8;

  {
    uint4 rbh = *(const uint4*)&Wt_hi[(size_t)bn * DF + bk];
    uint4 rbl = *(const uint4*)&Wt_lo[(size_t)bn * DF + bk];
    asm volatile("" ::: "memory");
#pragma unroll
    for (int i = 0; i < 4; ++i)
      glds16(x + asrc[i], (char*)Abuf[0] + wave * 4096 + i * 1024);
    *(uint4*)&Bhi[0][bn * BSTRIDE + bk] = rbh;
    *(uint4*)&Blo[0][bn * BSTRIDE + bk] = rbl;
    asm volatile("s_waitcnt lgkmcnt(0)" ::: "memory");
    __builtin_amdgcn_s_barrier();
  }

  for (int ks = 0; ks < 16; ++ks) {
    const int k0 = ks * 32;
    const int cur = ks & 1;
    uint4 rbh, rbl;
    if (ks < 15) {
      rbh = *(const uint4*)&Wt_hi[(size_t)bn * DF + k0 + 32 + bk];
      rbl = *(const uint4*)&Wt_lo[(size_t)bn * DF + k0 + 32 + bk];
      asm volatile("" ::: "memory");
#pragma unroll
      for (int i = 0; i < 4; ++i)
        glds16(x + asrc[i] + k0 + 32, (char*)Abuf[cur ^ 1] + wave * 4096 + i * 1024);
      asm volatile("s_waitcnt vmcnt(6)" ::: "memory");
    } else {
      asm volatile("s_waitcnt vmcnt(0)" ::: "memory");
    }
    short8v ah[2], al[2];
#pragma unroll
    for (int mt = 0; mt < 2; ++mt) {
      const float* p = Abuf[cur] + wave * 1024 + (mt * 16 + lm) * 32 + kg;
      float4 f0 = *(const float4*)p;
      float4 f1 = *(const float4*)(p + 4);
      float f[8] = {f0.x, f0.y, f0.z, f0.w, f1.x, f1.y, f1.z, f1.w};
#pragma unroll
      for (int c = 0; c < 8; ++c) {
        uint u = __float_as_uint(f[c]);
        ah[mt][c] = (short)(u >> 16);
        float hf = __uint_as_float(u & 0xFFFF0000u);
        al[mt][c] = (short)(__float_as_uint(f[c] - hf) >> 16);
      }
    }
    short8v bh[4], bl[4];
#pragma unroll
    for (int nt = 0; nt < 4; ++nt) {
      bh[nt] = *(const short8v*)&Bhi[cur][(nt * 16 + lm) * BSTRIDE + kg];
      bl[nt] = *(const short8v*)&Blo[cur][(nt * 16 + lm) * BSTRIDE + kg];
    }
#pragma unroll
    for (int mt = 0; mt < 2; ++mt)
#pragma unroll
      for (int nt = 0; nt < 4; ++nt) {
        acc[mt][nt] = __builtin_amdgcn_mfma_f32_16x16x32_bf16(ah[mt], bh[nt], acc[mt][nt], 0, 0, 0);
        acc[mt][nt] = __builtin_amdgcn_mfma_f32_16x16x32_bf16(ah[mt], bl[nt], acc[mt][nt], 0, 0, 0);
        acc[mt][nt] = __builtin_amdgcn_mfma_f32_16x16x32_bf16(al[mt], bh[nt], acc[mt][nt], 0, 0, 0);
      }
    if (ks < 15) {
      *(uint4*)&Bhi[cur ^ 1][bn * BSTRIDE + bk] = rbh;
      *(uint4*)&Blo[cur ^ 1][bn * BSTRIDE + bk] = rbl;
      asm volatile("s_waitcnt lgkmcnt(0)" ::: "memory");
    }
    __builtin_amdgcn_s_barrier();
  }

  __syncthreads();

#pragma unroll
  for (int mt = 0; mt < 2; ++mt)
#pragma unroll
    for (int nt = 0; nt < 4; ++nt)
#pragma unroll
      for (int r = 0; r < 4; ++r)
        Cs[(wm + mt * 16 + kq * 4 + r) * 65 + nt * 16 + lm] = acc[mt][nt][r];
  __syncthreads();

  {
    int row = tid >> 1, c0 = (tid & 1) * 32;
    int g = mb + row;
    if (g < NN) {
      uint u[16];
#pragma unroll
      for (int j = 0; j < 16; ++j) {
        uint p0 = f2bf(Cs[row * 65 + c0 + 2 * j]);
        uint p1 = f2bf(Cs[row * 65 + c0 + 2 * j + 1]);
        u[j] = p0 | (p1 << 16);
      }
#pragma unroll
      for (int q = 0; q < 4; ++q)
        *(uint4*)&h1b[(size_t)g * 64 + c0 + 8 * q] = *(uint4*)&u[4 * q];
      int half = tid & 1;
      float4 ssv, ddv;
      float* ssp = &ssv.x;
      float* ddp = &ddv.x;
#pragma unroll
      for (int hq = 0; hq < 4; ++hq) {
        int hh = half * 4 + hq;
        float ss = 0.f, dd = 0.f;
#pragma unroll
        for (int u8 = 0; u8 < 8; ++u8) {
          float hv = Cs[row * 65 + hh * 8 + u8];
          ss = fmaf(hv, a1s[hh * 8 + u8], ss);
          dd = fmaf(hv, a1d[hh * 8 + u8], dd);
        }
        ssp[hq] = ss; ddp[hq] = dd;
      }
      *(float4*)&s_src[(size_t)g * 8 + half * 4] = ssv;
      *(float4*)&s_dst[(size_t)g * 8 + half * 4] = ddv;
    }
  }
}

// ---------------- CSR scan ----------------
__global__ __launch_bounds__(NBKT) void bkt_scan_kernel(const int* __restrict__ bkt_cnt, int* __restrict__ bkt_base,
                                                        int* __restrict__ bkt_cursor, int* __restrict__ row_off) {
  __shared__ int s[NBKT];
  int tid = threadIdx.x;
  int v = bkt_cnt[tid];
  s[tid] = v;
  __syncthreads();
  for (int off = 1; off < NBKT; off <<= 1) {
    int t = (tid >= off) ? s[tid - off] : 0;
    __syncthreads();
    s[tid] += t;
    __syncthreads();
  }
  int excl = s[tid] - v;
  bkt_base[tid] = excl;
  bkt_cursor[tid] = excl;
  if (tid == NBKT - 1) bkt_base[NBKT] = s[tid];
  if (tid == 0) row_off[NN] = NE;
}

// ---------------- FUSED: layer-1 aggregation (64 nodes -> LDS, ELU, transposed) + layer-2 GEMM ----------------
// Phase 1: wave w aggregates nodes nb+w*16 .. +16 (agg1 body), writes elu(out) to As[k=lane][m] (stride 68).
// Phase 2: gemm2 (BM=64, BN=128) with A from LDS; fused bf16 h2b write + register scores -> s2src/s2dst.
// Layer-2 scores go to SEPARATE buffers (other blocks still read layer-1 scores in phase 1).
__global__ __launch_bounds__(256) void agg1_gemm2(const int* __restrict__ row_off, const int* __restrict__ srcs,
                                                  const float* __restrict__ s_src, const float* __restrict__ s_dst,
                                                  const __hip_bfloat16* __restrict__ hb,
                                                  const float* __restrict__ B,      // W2 [64][128]
                                                  __hip_bfloat162* __restrict__ Cb, // h2b
                                                  const float* __restrict__ a2s, const float* __restrict__ a2d,
                                                  float* __restrict__ s2src, float* __restrict__ s2dst) {
  __shared__ float As[64 * 68];                // As[k][m], stride 68 (16B-aligned rows)
  __shared__ float Bs[32 * 136];
  const int tid = threadIdx.x;
  const int nb = blockIdx.x * 64;
  const int wave = tid >> 6, lane = tid & 63;
  const int hh = lane >> 3;

  // ---- phase 1: aggregate 16 nodes per wave ----
  for (int t = 0; t < 16; ++t) {
    int local_m = wave * 16 + t;
    int node = nb + local_m;
    float r = 0.f;
    if (node < NN) {
      float sd = s_dst[(size_t)node * 8 + hh];
      int beg = row_off[node], end = row_off[node + 1];
      float acc = 0.f, den = 0.f;
      int i = beg;
      for (; i + 8 <= end; i += 8) {
        int s[8];
#pragma unroll
        for (int j = 0; j < 8; ++j) s[j] = srcs[i + j];
        float e[8], hv[8];
#pragma unroll
        for (int j = 0; j < 8; ++j) e[j] = s_src[(size_t)s[j] * 8 + hh];
#pragma unroll
        for (int j = 0; j < 8; ++j) hv[j] = __bfloat162float(hb[(size_t)s[j] * 64 + lane]);
#pragma unroll
        for (int j = 0; j < 8; ++j) {
          float xj = __expf(lrelu(sd + e[j]));
          den += xj;
          acc = fmaf(xj, hv[j], acc);
        }
      }
      for (; i < end; ++i) {
        int s0 = srcs[i];
        float x0 = __expf(lrelu(sd + s_src[(size_t)s0 * 8 + hh]));
        den += x0;
        acc = fmaf(x0, __bfloat162float(hb[(size_t)s0 * 64 + lane]), acc);
      }
      r = eluf(acc / fmaxf(den, 1e-9f));
    }
    As[lane * 68 + local_m] = r;               // transposed + ELU'd
  }
  __syncthreads();

  // ---- phase 2: gemm2 from LDS ----
  const int tx = tid & 15, ty = tid >> 4;
  float acc[4][8] = {};
  for (int k0 = 0; k0 < 64; k0 += 32) {
    for (int j = tid; j < 1024; j += 256) {    // B tile 32x128
      int kr = j >> 5, nq = j & 31;
      *(float4*)&Bs[kr * 136 + nq * 4] = *(const float4*)&B[(size_t)(k0 + kr) * 128 + nq * 4];
    }
    __syncthreads();
#pragma unroll
    for (int kk = 0; kk < 32; ++kk) {
      float4 a4 = *(const float4*)&As[(k0 + kk) * 68 + ty * 4];
      float4 b0 = *(const float4*)&Bs[kk * 136 + tx * 8];
      float4 b1 = *(const float4*)&Bs[kk * 136 + tx * 8 + 4];
      float av[4] = {a4.x, a4.y, a4.z, a4.w};
      float bv[8] = {b0.x, b0.y, b0.z, b0.w, b1.x, b1.y, b1.z, b1.w};
#pragma unroll
      for (int i = 0; i < 4; ++i)
#pragma unroll
        for (int jj = 0; jj < 8; ++jj)
          acc[i][jj] = fmaf(av[i], bv[jj], acc[i][jj]);
    }
    __syncthreads();
  }
  const int hx = tx >> 1, half8 = (tx & 1) * 8;
#pragma unroll
  for (int i = 0; i < 4; ++i) {
    int row = nb + ty * 4 + i;
    float ss = 0.f, dd = 0.f;
#pragma unroll
    for (int c = 0; c < 8; ++c) {
      ss = fmaf(acc[i][c], a2s[hx * 16 + half8 + c], ss);
      dd = fmaf(acc[i][c], a2d[hx * 16 + half8 + c], dd);
    }
    ss += __shfl_xor(ss, 1, 64);
    dd += __shfl_xor(dd, 1, 64);
    if (row < NN) {
      uint u[4];
#pragma unroll
      for (int q = 0; q < 4; ++q)
        u[q] = (uint)f2bf(acc[i][2 * q]) | ((uint)f2bf(acc[i][2 * q + 1]) << 16);
      *(uint4*)&Cb[(size_t)row * 64 + tx * 4] = *(uint4*)u;
      if ((tx & 1) == 0) {
        s2src[(size_t)row * 8 + hx] = ss;
        s2dst[(size_t)row * 8 + hx] = dd;
      }
    }
  }
}

// ---------------- layer-2 aggregation over INDICES only + head average ----------------
__global__ __launch_bounds__(256) void agg2_idx_kernel(const int* __restrict__ row_off, const int* __restrict__ srcs,
                                                       const float* __restrict__ s_src, const float* __restrict__ s_dst,
                                                       const __hip_bfloat162* __restrict__ h2b, const int* __restrict__ idx,
                                                       float* __restrict__ out, int ni) {
  int w = (blockIdx.x * 256 + threadIdx.x) >> 6;
  int lane = threadIdx.x & 63;
  if (w >= ni) return;
  int node = idx[w];
  int hh = lane >> 3, o2 = lane & 7;
  float sd = s_dst[(size_t)node * 8 + hh];
  int beg = row_off[node], end = row_off[node + 1];
  float a0 = 0.f, a1 = 0.f, den = 0.f;
  int i = beg;
  for (; i + 4 <= end; i += 4) {
    int s0 = srcs[i], s1 = srcs[i + 1], s2 = srcs[i + 2], s3 = srcs[i + 3];
    float e0 = s_src[(size_t)s0 * 8 + hh];
    float e1 = s_src[(size_t)s1 * 8 + hh];
    float e2 = s_src[(size_t)s2 * 8 + hh];
    float e3 = s_src[(size_t)s3 * 8 + hh];
    float2 v0 = __bfloat1622float2(h2b[(size_t)s0 * 64 + hh * 8 + o2]);
    float2 v1 = __bfloat1622float2(h2b[(size_t)s1 * 64 + hh * 8 + o2]);
    float2 v2 = __bfloat1622float2(h2b[(size_t)s2 * 64 + hh * 8 + o2]);
    float2 v3 = __bfloat1622float2(h2b[(size_t)s3 * 64 + hh * 8 + o2]);
    float x0 = __expf(lrelu(sd + e0));
    float x1 = __expf(lrelu(sd + e1));
    float x2 = __expf(lrelu(sd + e2));
    float x3 = __expf(lrelu(sd + e3));
    den += (x0 + x1) + (x2 + x3);
    a0 = fmaf(x0, v0.x, fmaf(x1, v1.x, fmaf(x2, v2.x, fmaf(x3, v3.x, a0))));
    a1 = fmaf(x0, v0.y, fmaf(x1, v1.y, fmaf(x2, v2.y, fmaf(x3, v3.y, a1))));
  }
  for (; i < end; ++i) {
    int s0 = srcs[i];
    float x0 = __expf(lrelu(sd + s_src[(size_t)s0 * 8 + hh]));
    float2 v0 = __bfloat1622float2(h2b[(size_t)s0 * 64 + hh * 8 + o2]);
    den += x0;
    a0 = fmaf(x0, v0.x, a0);
    a1 = fmaf(x0, v0.y, a1);
  }
  float r0 = a0 / fmaxf(den, 1e-9f);
  float r1 = a1 / fmaxf(den, 1e-9f);
  for (int m = 8; m < 64; m <<= 1) {
    r0 += __shfl_xor(r0, m, 64);
    r1 += __shfl_xor(r1, m, 64);
  }
  if (lane < 8) {
    float2 wv = make_float2(r0 * 0.125f, r1 * 0.125f);
    *(float2*)&out[(size_t)w * 16 + lane * 2] = wv;
  }
}

extern "C" void kernel_launch(void* const* d_in, const int* in_sizes, int n_in,
                              void* d_out, int out_size, void* d_ws, size_t ws_size,
                              hipStream_t stream) {
  const float* x   = (const float*)d_in[0];
  const int2* edges = (const int2*)d_in[1];
  const int* indices = (const int*)d_in[2];
  const float* W1  = (const float*)d_in[3];
  const float* a1s = (const float*)d_in[4];
  const float* a1d = (const float*)d_in[5];
  const float* W2  = (const float*)d_in[6];
  const float* a2s = (const float*)d_in[7];
  const float* a2d = (const float*)d_in[8];
  float* out = (float*)d_out;

  char* ws = (char*)d_ws;
  size_t off = 0;
  auto alloc = [&](size_t bytes) {
    void* p = ws + off;
    off = (off + bytes + 255) & ~(size_t)255;
    return p;
  };
  float* s1src = (float*)alloc((size_t)NN * 8 * 4);
  float* s1dst = (float*)alloc((size_t)NN * 8 * 4);
  float* s2src = (float*)alloc((size_t)NN * 8 * 4);
  float* s2dst = (float*)alloc((size_t)NN * 8 * 4);
  ushort* h1b  = (ushort*)alloc((size_t)NN * 64 * 2);
  __hip_bfloat162* h2b = (__hip_bfloat162*)alloc((size_t)NN * 128 * 2);
  int* row_off = (int*)alloc(((size_t)NN + 1) * 4);
  int* ssrc    = (int*)alloc((size_t)NE * 4);
  uint* pairs  = (uint*)alloc((size_t)NE * 4);
  ushort* Wt_hi = (ushort*)alloc((size_t)DF * 64 * 2);
  ushort* Wt_lo = (ushort*)alloc((size_t)DF * 64 * 2);
  int* bkt_cnt    = (int*)alloc(NBKT * 4);
  int* bkt_base   = (int*)alloc((NBKT + 1) * 4);
  int* bkt_cursor = (int*)alloc(NBKT * 4);

  hipMemsetAsync(bkt_cnt, 0, NBKT * 4, stream);

  dim3 b256(256);
  // 1) W1 split/transpose + edge histogram (co-scheduled)
  prep_w_hist<<<dim3(128 + NBKT), b256, 0, stream>>>(W1, Wt_hi, Wt_lo, edges, bkt_cnt);
  // 2) bucket scan
  bkt_scan_kernel<<<dim3(1), dim3(NBKT), 0, stream>>>(bkt_cnt, bkt_base, bkt_cursor, row_off);
  // 3) gemm1 first half || bucket reorder
  gemm1_mix<0><<<dim3(GEMM1A + NBKT), b256, 0, stream>>>(x, Wt_hi, Wt_lo, a1s, a1d, h1b, s1src, s1dst,
                                                         GEMM1A, 0, edges, bkt_cursor, pairs,
                                                         bkt_base, row_off, ssrc);
  // 4) gemm1 second half || bucket build
  gemm1_mix<1><<<dim3(GEMM1B + NBKT), b256, 0, stream>>>(x, Wt_hi, Wt_lo, a1s, a1d, h1b, s1src, s1dst,
                                                         GEMM1B, GEMM1A, edges, bkt_cursor, pairs,
                                                         bkt_base, row_off, ssrc);
  // 5) FUSED layer-1 aggregation + layer-2 GEMM (ELU + bf16 h2b + layer-2 scores -> s2)
  agg1_gemm2<<<dim3((NN + 63) / 64), b256, 0, stream>>>(row_off, ssrc, s1src, s1dst,
                                                        (const __hip_bfloat16*)h1b, W2, h2b, a2s, a2d,
                                                        s2src, s2dst);
  // 6) layer 2 aggregation over the 10k output indices only
  agg2_idx_kernel<<<dim3((NIDX * 64 + 255) / 256), b256, 0, stream>>>(row_off, ssrc, s2src, s2dst, h2b, indices, out, NIDX);
}

// Round 18
// 245.659 us; speedup vs baseline: 1.3870x; 1.3870x over previous
//
#include <hip/hip_runtime.h>
#include <hip/hip_bf16.h>

#define NN 100000
#define NE 1600000
#define DF 512
#define NIDX 10000

#define NBKT 512
#define BKT_W 196                 // ceil(100000/512); 512*196 = 100352 >= NN
#define EDGES_PER_BKT_BLK 3125    // NE / 512 exactly
#define GEMM1_NB 782              // (NN+127)/128
#define GEMM1A 391                // first-half blocks
#define GEMM1B (GEMM1_NB - GEMM1A)

typedef __attribute__((ext_vector_type(8))) short short8v;
typedef __attribute__((ext_vector_type(4))) float float4v;

__device__ __forceinline__ float eluf(float x) { return x > 0.f ? x : expm1f(x); }
__device__ __forceinline__ float lrelu(float x) { return x > 0.f ? x : 0.2f * x; }
__device__ __forceinline__ ushort f2bf(float f) {
  __hip_bfloat16 b = __float2bfloat16(f);
  return *(ushort*)&b;
}

// global_load_lds: 16B per lane, dest = uniform LDS base + lane*16 (CK cast pattern)
__device__ __forceinline__ void glds16(const void* gsrc, void* ldst) {
  __builtin_amdgcn_global_load_lds(
      (const __attribute__((address_space(1))) uint32_t*)(uintptr_t)gsrc,
      (__attribute__((address_space(3))) uint32_t*)(uintptr_t)ldst, 16, 0, 0);
}

// ---------------- prep_w (blocks 0..127) + edge histogram (blocks 128..639) ----------------
__global__ __launch_bounds__(256) void prep_w_hist(const float* __restrict__ W1,
                                                   ushort* __restrict__ Wt_hi, ushort* __restrict__ Wt_lo,
                                                   const int2* __restrict__ edges, int* __restrict__ bkt_cnt) {
  const int tid = threadIdx.x;
  if (blockIdx.x >= 128) {
    __shared__ int h[NBKT];
    h[tid] = 0; h[tid + 256] = 0;
    __syncthreads();
    const int b = blockIdx.x - 128;
    const int i0 = b * EDGES_PER_BKT_BLK;
    const int i1 = min(i0 + EDGES_PER_BKT_BLK, NE);
    for (int i = i0 + tid; i < i1; i += 256) atomicAdd(&h[edges[i].x / BKT_W], 1);
    __syncthreads();
    if (h[tid]) atomicAdd(&bkt_cnt[tid], h[tid]);
    if (h[tid + 256]) atomicAdd(&bkt_cnt[tid + 256], h[tid + 256]);
    return;
  }
  int t = blockIdx.x * 256 + tid;          // t < 32768 = DF*64
  int k = t >> 6, n = t & 63;
  float w = W1[t];
  ushort hi = f2bf(w);
  __hip_bfloat16 hb = *(__hip_bfloat16*)&hi;
  ushort lo = f2bf(w - __bfloat162float(hb));
  Wt_hi[(size_t)n * DF + k] = hi;
  Wt_lo[(size_t)n * DF + k] = lo;
}

// ---------------- layer-1 GEMM half + co-scheduled CSR tail ----------------
// TAIL=0: blocks >= gemm_cnt run bucket REORDER (needs scan done in a prior launch).
// TAIL=1: blocks >= gemm_cnt run bucket BUILD (needs pairs from the reorder launch).
// GEMM path: counted-vmcnt pipeline (A wave-local glds dbuf, B LDS dbuf, raw s_barrier).
#define BSTRIDE 40
template<int TAIL>
__global__ __launch_bounds__(256) void gemm1_mix(const float* __restrict__ x,
                                                 const ushort* __restrict__ Wt_hi, const ushort* __restrict__ Wt_lo,
                                                 const float* __restrict__ a1s, const float* __restrict__ a1d,
                                                 ushort* __restrict__ h1b, float* __restrict__ s_src,
                                                 float* __restrict__ s_dst,
                                                 int gemm_cnt, int gemm_off,
                                                 const int2* __restrict__ edges, int* __restrict__ bkt_cursor,
                                                 uint* __restrict__ pairs,
                                                 const int* __restrict__ bkt_base, int* __restrict__ row_off,
                                                 int* __restrict__ ssrc) {
  __shared__ __align__(16) char smem[53248];
  const int tid = threadIdx.x;

  if (blockIdx.x >= (unsigned)gemm_cnt) {
    const int tb = blockIdx.x - gemm_cnt;
    if (TAIL == 0) {
      // ---- bucket reorder ----
      int* h = (int*)smem;
      int* lbase = h + NBKT;
      int* cur = lbase + NBKT;
      h[tid] = 0; h[tid + 256] = 0;
      __syncthreads();
      const int i0 = tb * EDGES_PER_BKT_BLK;
      const int i1 = min(i0 + EDGES_PER_BKT_BLK, NE);
      for (int i = i0 + tid; i < i1; i += 256) atomicAdd(&h[edges[i].x / BKT_W], 1);
      __syncthreads();
#pragma unroll
      for (int q = 0; q < 2; ++q) {
        int b = tid + q * 256;
        int c = h[b];
        lbase[b] = c ? atomicAdd(&bkt_cursor[b], c) : 0;
        cur[b] = 0;
      }
      __syncthreads();
      for (int i = i0 + tid; i < i1; i += 256) {
        int2 e = edges[i];
        int bk = e.x / BKT_W;
        int r = atomicAdd(&cur[bk], 1);
        pairs[lbase[bk] + r] = ((uint)(e.x - bk * BKT_W) << 24) | (uint)e.y;
      }
    } else {
      // ---- bucket build ----
      int* hist = (int*)smem;
      int* ts = hist + 256;
      int* cur = ts + 256;
      const int d0 = tb * BKT_W;
      if (d0 >= NN) return;
      const int nd = min(BKT_W, NN - d0);
      const int beg = bkt_base[tb], end = bkt_base[tb + 1];
      hist[tid] = 0;
      __syncthreads();
      for (int i = beg + tid; i < end; i += 256) atomicAdd(&hist[pairs[i] >> 24], 1);
      __syncthreads();
      int v = hist[tid];
      ts[tid] = v;
      __syncthreads();
      for (int off = 1; off < 256; off <<= 1) {
        int t2 = (tid >= off) ? ts[tid - off] : 0;
        __syncthreads();
        ts[tid] += t2;
        __syncthreads();
      }
      int excl = ts[tid] - v;
      if (tid < nd) row_off[d0 + tid] = beg + excl;
      cur[tid] = beg + excl;
      __syncthreads();
      for (int i = beg + tid; i < end; i += 256) {
        uint p = pairs[i];
        int pos = atomicAdd(&cur[p >> 24], 1);
        ssrc[pos] = (int)(p & 0xFFFFFFu);
      }
    }
    return;
  }

  // ---- GEMM path ----
  float* Abuf[2];
  Abuf[0] = (float*)smem;
  Abuf[1] = (float*)(smem + 16384);
  ushort* Bhi[2]; ushort* Blo[2];
  Bhi[0] = (ushort*)(smem + 32768);
  Blo[0] = Bhi[0] + 64 * BSTRIDE;
  Bhi[1] = Blo[0] + 64 * BSTRIDE;
  Blo[1] = Bhi[1] + 64 * BSTRIDE;
  float* Cs = (float*)smem;                    // epilogue alias, stride 65

  const int mb = (gemm_off + blockIdx.x) * 128;
  const int wave = tid >> 6, l = tid & 63;
  const int wm = wave * 32;
  const int lm = l & 15, kq = l >> 4, kg = kq * 8;

  float4v acc[2][4];
#pragma unroll
  for (int i = 0; i < 2; ++i)
#pragma unroll
    for (int j = 0; j < 4; ++j) acc[i][j] = (float4v){0.f, 0.f, 0.f, 0.f};

  size_t asrc[4];
#pragma unroll
  for (int i = 0; i < 4; ++i) {
    int g = mb + wm + 8 * i + (l >> 3);
    if (g > NN - 1) g = NN - 1;
    asrc[i] = (size_t)g * DF + (l & 7) * 4;
  }
  const int bn = tid & 63, bk = (tid >> 6) * 8;

  {
    uint4 rbh = *(const uint4*)&Wt_hi[(size_t)bn * DF + bk];
    uint4 rbl = *(const uint4*)&Wt_lo[(size_t)bn * DF + bk];
    asm volatile("" ::: "memory");
#pragma unroll
    for (int i = 0; i < 4; ++i)
      glds16(x + asrc[i], (char*)Abuf[0] + wave * 4096 + i * 1024);
    *(uint4*)&Bhi[0][bn * BSTRIDE + bk] = rbh;
    *(uint4*)&Blo[0][bn * BSTRIDE + bk] = rbl;
    asm volatile("s_waitcnt lgkmcnt(0)" ::: "memory");
    __builtin_amdgcn_s_barrier();
  }

  for (int ks = 0; ks < 16; ++ks) {
    const int k0 = ks * 32;
    const int cur = ks & 1;
    uint4 rbh, rbl;
    if (ks < 15) {
      rbh = *(const uint4*)&Wt_hi[(size_t)bn * DF + k0 + 32 + bk];
      rbl = *(const uint4*)&Wt_lo[(size_t)bn * DF + k0 + 32 + bk];
      asm volatile("" ::: "memory");
#pragma unroll
      for (int i = 0; i < 4; ++i)
        glds16(x + asrc[i] + k0 + 32, (char*)Abuf[cur ^ 1] + wave * 4096 + i * 1024);
      asm volatile("s_waitcnt vmcnt(6)" ::: "memory");
    } else {
      asm volatile("s_waitcnt vmcnt(0)" ::: "memory");
    }
    short8v ah[2], al[2];
#pragma unroll
    for (int mt = 0; mt < 2; ++mt) {
      const float* p = Abuf[cur] + wave * 1024 + (mt * 16 + lm) * 32 + kg;
      float4 f0 = *(const float4*)p;
      float4 f1 = *(const float4*)(p + 4);
      float f[8] = {f0.x, f0.y, f0.z, f0.w, f1.x, f1.y, f1.z, f1.w};
#pragma unroll
      for (int c = 0; c < 8; ++c) {
        uint u = __float_as_uint(f[c]);
        ah[mt][c] = (short)(u >> 16);
        float hf = __uint_as_float(u & 0xFFFF0000u);
        al[mt][c] = (short)(__float_as_uint(f[c] - hf) >> 16);
      }
    }
    short8v bh[4], bl[4];
#pragma unroll
    for (int nt = 0; nt < 4; ++nt) {
      bh[nt] = *(const short8v*)&Bhi[cur][(nt * 16 + lm) * BSTRIDE + kg];
      bl[nt] = *(const short8v*)&Blo[cur][(nt * 16 + lm) * BSTRIDE + kg];
    }
#pragma unroll
    for (int mt = 0; mt < 2; ++mt)
#pragma unroll
      for (int nt = 0; nt < 4; ++nt) {
        acc[mt][nt] = __builtin_amdgcn_mfma_f32_16x16x32_bf16(ah[mt], bh[nt], acc[mt][nt], 0, 0, 0);
        acc[mt][nt] = __builtin_amdgcn_mfma_f32_16x16x32_bf16(ah[mt], bl[nt], acc[mt][nt], 0, 0, 0);
        acc[mt][nt] = __builtin_amdgcn_mfma_f32_16x16x32_bf16(al[mt], bh[nt], acc[mt][nt], 0, 0, 0);
      }
    if (ks < 15) {
      *(uint4*)&Bhi[cur ^ 1][bn * BSTRIDE + bk] = rbh;
      *(uint4*)&Blo[cur ^ 1][bn * BSTRIDE + bk] = rbl;
      asm volatile("s_waitcnt lgkmcnt(0)" ::: "memory");
    }
    __builtin_amdgcn_s_barrier();
  }

  __syncthreads();

#pragma unroll
  for (int mt = 0; mt < 2; ++mt)
#pragma unroll
    for (int nt = 0; nt < 4; ++nt)
#pragma unroll
      for (int r = 0; r < 4; ++r)
        Cs[(wm + mt * 16 + kq * 4 + r) * 65 + nt * 16 + lm] = acc[mt][nt][r];
  __syncthreads();

  {
    int row = tid >> 1, c0 = (tid & 1) * 32;
    int g = mb + row;
    if (g < NN) {
      uint u[16];
#pragma unroll
      for (int j = 0; j < 16; ++j) {
        uint p0 = f2bf(Cs[row * 65 + c0 + 2 * j]);
        uint p1 = f2bf(Cs[row * 65 + c0 + 2 * j + 1]);
        u[j] = p0 | (p1 << 16);
      }
#pragma unroll
      for (int q = 0; q < 4; ++q)
        *(uint4*)&h1b[(size_t)g * 64 + c0 + 8 * q] = *(uint4*)&u[4 * q];
      int half = tid & 1;
      float4 ssv, ddv;
      float* ssp = &ssv.x;
      float* ddp = &ddv.x;
#pragma unroll
      for (int hq = 0; hq < 4; ++hq) {
        int hh = half * 4 + hq;
        float ss = 0.f, dd = 0.f;
#pragma unroll
        for (int u8 = 0; u8 < 8; ++u8) {
          float hv = Cs[row * 65 + hh * 8 + u8];
          ss = fmaf(hv, a1s[hh * 8 + u8], ss);
          dd = fmaf(hv, a1d[hh * 8 + u8], dd);
        }
        ssp[hq] = ss; ddp[hq] = dd;
      }
      *(float4*)&s_src[(size_t)g * 8 + half * 4] = ssv;
      *(float4*)&s_dst[(size_t)g * 8 + half * 4] = ddv;
    }
  }
}

// ---------------- CSR scan ----------------
__global__ __launch_bounds__(NBKT) void bkt_scan_kernel(const int* __restrict__ bkt_cnt, int* __restrict__ bkt_base,
                                                        int* __restrict__ bkt_cursor, int* __restrict__ row_off) {
  __shared__ int s[NBKT];
  int tid = threadIdx.x;
  int v = bkt_cnt[tid];
  s[tid] = v;
  __syncthreads();
  for (int off = 1; off < NBKT; off <<= 1) {
    int t = (tid >= off) ? s[tid - off] : 0;
    __syncthreads();
    s[tid] += t;
    __syncthreads();
  }
  int excl = s[tid] - v;
  bkt_base[tid] = excl;
  bkt_cursor[tid] = excl;
  if (tid == NBKT - 1) bkt_base[NBKT] = s[tid];
  if (tid == 0) row_off[NN] = NE;
}

// ---------------- layer-2 GEMM: BM=64, BN=128, fused ELU + bf16 write + register scores ----------------
__global__ __launch_bounds__(256) void gemm2_fused(const float* __restrict__ A, const float* __restrict__ B,
                                                   __hip_bfloat162* __restrict__ Cb,
                                                   const float* __restrict__ a2s, const float* __restrict__ a2d,
                                                   float* __restrict__ s_src, float* __restrict__ s_dst,
                                                   int M) {
  __shared__ float sm[6528];                   // As[32][68] | Bs[32][136]
  float* As = sm;
  float* Bs = sm + 32 * 68;
  const int tid = threadIdx.x;
  const int m0 = blockIdx.x * 64;
  const int tx = tid & 15, ty = tid >> 4;
  float acc[4][8] = {};
  for (int k0 = 0; k0 < 64; k0 += 32) {
    for (int j = tid; j < 512; j += 256) {
      int r = j >> 3, kq = j & 7;
      int row = m0 + r;
      float4 v = make_float4(0.f, 0.f, 0.f, 0.f);
      if (row < M) v = *(const float4*)&A[(size_t)row * 64 + k0 + kq * 4];
      v.x = eluf(v.x); v.y = eluf(v.y); v.z = eluf(v.z); v.w = eluf(v.w);
      As[(kq * 4 + 0) * 68 + r] = v.x; As[(kq * 4 + 1) * 68 + r] = v.y;
      As[(kq * 4 + 2) * 68 + r] = v.z; As[(kq * 4 + 3) * 68 + r] = v.w;
    }
    for (int j = tid; j < 1024; j += 256) {
      int kr = j >> 5, nq = j & 31;
      *(float4*)&Bs[kr * 136 + nq * 4] = *(const float4*)&B[(size_t)(k0 + kr) * 128 + nq * 4];
    }
    __syncthreads();
#pragma unroll
    for (int kk = 0; kk < 32; ++kk) {
      float4 a4 = *(const float4*)&As[kk * 68 + ty * 4];
      float4 b0 = *(const float4*)&Bs[kk * 136 + tx * 8];
      float4 b1 = *(const float4*)&Bs[kk * 136 + tx * 8 + 4];
      float av[4] = {a4.x, a4.y, a4.z, a4.w};
      float bv[8] = {b0.x, b0.y, b0.z, b0.w, b1.x, b1.y, b1.z, b1.w};
#pragma unroll
      for (int i = 0; i < 4; ++i)
#pragma unroll
        for (int jj = 0; jj < 8; ++jj)
          acc[i][jj] = fmaf(av[i], bv[jj], acc[i][jj]);
    }
    __syncthreads();
  }
  const int hx = tx >> 1, half8 = (tx & 1) * 8;
#pragma unroll
  for (int i = 0; i < 4; ++i) {
    int row = m0 + ty * 4 + i;
    float ss = 0.f, dd = 0.f;
#pragma unroll
    for (int c = 0; c < 8; ++c) {
      ss = fmaf(acc[i][c], a2s[hx * 16 + half8 + c], ss);
      dd = fmaf(acc[i][c], a2d[hx * 16 + half8 + c], dd);
    }
    ss += __shfl_xor(ss, 1, 64);
    dd += __shfl_xor(dd, 1, 64);
    if (row < M) {
      uint u[4];
#pragma unroll
      for (int q = 0; q < 4; ++q)
        u[q] = (uint)f2bf(acc[i][2 * q]) | ((uint)f2bf(acc[i][2 * q + 1]) << 16);
      *(uint4*)&Cb[(size_t)row * 64 + tx * 4] = *(uint4*)u;
      if ((tx & 1) == 0) {
        s_src[(size_t)row * 8 + hx] = ss;
        s_dst[(size_t)row * 8 + hx] = dd;
      }
    }
  }
}

// ---------------- layer-1 aggregation: wave per node, 8-edge unroll, bf16 values ----------------
__global__ __launch_bounds__(256) void agg1_kernel(const int* __restrict__ row_off, const int* __restrict__ srcs,
                                                   const float* __restrict__ s_src, const float* __restrict__ s_dst,
                                                   const __hip_bfloat16* __restrict__ hb, float* __restrict__ out, int n) {
  int wave = (blockIdx.x * 256 + threadIdx.x) >> 6;
  int lane = threadIdx.x & 63;
  if (wave >= n) return;
  int hh = lane >> 3;
  float sd = s_dst[(size_t)wave * 8 + hh];
  int beg = row_off[wave], end = row_off[wave + 1];
  float acc = 0.f, den = 0.f;
  int i = beg;
  for (; i + 8 <= end; i += 8) {
    int s[8];
#pragma unroll
    for (int j = 0; j < 8; ++j) s[j] = srcs[i + j];
    float e[8], hv[8];
#pragma unroll
    for (int j = 0; j < 8; ++j) e[j] = s_src[(size_t)s[j] * 8 + hh];
#pragma unroll
    for (int j = 0; j < 8; ++j) hv[j] = __bfloat162float(hb[(size_t)s[j] * 64 + lane]);
#pragma unroll
    for (int j = 0; j < 8; ++j) {
      float xj = __expf(lrelu(sd + e[j]));
      den += xj;
      acc = fmaf(xj, hv[j], acc);
    }
  }
  for (; i < end; ++i) {
    int s0 = srcs[i];
    float x0 = __expf(lrelu(sd + s_src[(size_t)s0 * 8 + hh]));
    den += x0;
    acc = fmaf(x0, __bfloat162float(hb[(size_t)s0 * 64 + lane]), acc);
  }
  out[(size_t)wave * 64 + lane] = acc / fmaxf(den, 1e-9f);
}

// ---------------- layer-2 aggregation over INDICES only + head average ----------------
__global__ __launch_bounds__(256) void agg2_idx_kernel(const int* __restrict__ row_off, const int* __restrict__ srcs,
                                                       const float* __restrict__ s_src, const float* __restrict__ s_dst,
                                                       const __hip_bfloat162* __restrict__ h2b, const int* __restrict__ idx,
                                                       float* __restrict__ out, int ni) {
  int w = (blockIdx.x * 256 + threadIdx.x) >> 6;
  int lane = threadIdx.x & 63;
  if (w >= ni) return;
  int node = idx[w];
  int hh = lane >> 3, o2 = lane & 7;
  float sd = s_dst[(size_t)node * 8 + hh];
  int beg = row_off[node], end = row_off[node + 1];
  float a0 = 0.f, a1 = 0.f, den = 0.f;
  int i = beg;
  for (; i + 4 <= end; i += 4) {
    int s0 = srcs[i], s1 = srcs[i + 1], s2 = srcs[i + 2], s3 = srcs[i + 3];
    float e0 = s_src[(size_t)s0 * 8 + hh];
    float e1 = s_src[(size_t)s1 * 8 + hh];
    float e2 = s_src[(size_t)s2 * 8 + hh];
    float e3 = s_src[(size_t)s3 * 8 + hh];
    float2 v0 = __bfloat1622float2(h2b[(size_t)s0 * 64 + hh * 8 + o2]);
    float2 v1 = __bfloat1622float2(h2b[(size_t)s1 * 64 + hh * 8 + o2]);
    float2 v2 = __bfloat1622float2(h2b[(size_t)s2 * 64 + hh * 8 + o2]);
    float2 v3 = __bfloat1622float2(h2b[(size_t)s3 * 64 + hh * 8 + o2]);
    float x0 = __expf(lrelu(sd + e0));
    float x1 = __expf(lrelu(sd + e1));
    float x2 = __expf(lrelu(sd + e2));
    float x3 = __expf(lrelu(sd + e3));
    den += (x0 + x1) + (x2 + x3);
    a0 = fmaf(x0, v0.x, fmaf(x1, v1.x, fmaf(x2, v2.x, fmaf(x3, v3.x, a0))));
    a1 = fmaf(x0, v0.y, fmaf(x1, v1.y, fmaf(x2, v2.y, fmaf(x3, v3.y, a1))));
  }
  for (; i < end; ++i) {
    int s0 = srcs[i];
    float x0 = __expf(lrelu(sd + s_src[(size_t)s0 * 8 + hh]));
    float2 v0 = __bfloat1622float2(h2b[(size_t)s0 * 64 + hh * 8 + o2]);
    den += x0;
    a0 = fmaf(x0, v0.x, a0);
    a1 = fmaf(x0, v0.y, a1);
  }
  float r0 = a0 / fmaxf(den, 1e-9f);
  float r1 = a1 / fmaxf(den, 1e-9f);
  for (int m = 8; m < 64; m <<= 1) {
    r0 += __shfl_xor(r0, m, 64);
    r1 += __shfl_xor(r1, m, 64);
  }
  if (lane < 8) {
    float2 wv = make_float2(r0 * 0.125f, r1 * 0.125f);
    *(float2*)&out[(size_t)w * 16 + lane * 2] = wv;
  }
}

extern "C" void kernel_launch(void* const* d_in, const int* in_sizes, int n_in,
                              void* d_out, int out_size, void* d_ws, size_t ws_size,
                              hipStream_t stream) {
  const float* x   = (const float*)d_in[0];
  const int2* edges = (const int2*)d_in[1];
  const int* indices = (const int*)d_in[2];
  const float* W1  = (const float*)d_in[3];
  const float* a1s = (const float*)d_in[4];
  const float* a1d = (const float*)d_in[5];
  const float* W2  = (const float*)d_in[6];
  const float* a2s = (const float*)d_in[7];
  const float* a2d = (const float*)d_in[8];
  float* out = (float*)d_out;

  char* ws = (char*)d_ws;
  size_t off = 0;
  auto alloc = [&](size_t bytes) {
    void* p = ws + off;
    off = (off + bytes + 255) & ~(size_t)255;
    return p;
  };
  float* s1src = (float*)alloc((size_t)NN * 8 * 4);
  float* s1dst = (float*)alloc((size_t)NN * 8 * 4);
  float* out1  = (float*)alloc((size_t)NN * 64 * 4);
  ushort* h1b  = (ushort*)alloc((size_t)NN * 64 * 2);
  __hip_bfloat162* h2b = (__hip_bfloat162*)alloc((size_t)NN * 128 * 2);
  int* row_off = (int*)alloc(((size_t)NN + 1) * 4);
  int* ssrc    = (int*)alloc((size_t)NE * 4);
  uint* pairs  = (uint*)alloc((size_t)NE * 4);
  ushort* Wt_hi = (ushort*)alloc((size_t)DF * 64 * 2);
  ushort* Wt_lo = (ushort*)alloc((size_t)DF * 64 * 2);
  int* bkt_cnt    = (int*)alloc(NBKT * 4);
  int* bkt_base   = (int*)alloc((NBKT + 1) * 4);
  int* bkt_cursor = (int*)alloc(NBKT * 4);

  hipMemsetAsync(bkt_cnt, 0, NBKT * 4, stream);

  dim3 b256(256);
  // 1) W1 split/transpose + edge histogram (co-scheduled)
  prep_w_hist<<<dim3(128 + NBKT), b256, 0, stream>>>(W1, Wt_hi, Wt_lo, edges, bkt_cnt);
  // 2) bucket scan
  bkt_scan_kernel<<<dim3(1), dim3(NBKT), 0, stream>>>(bkt_cnt, bkt_base, bkt_cursor, row_off);
  // 3) gemm1 first half || bucket reorder
  gemm1_mix<0><<<dim3(GEMM1A + NBKT), b256, 0, stream>>>(x, Wt_hi, Wt_lo, a1s, a1d, h1b, s1src, s1dst,
                                                         GEMM1A, 0, edges, bkt_cursor, pairs,
                                                         bkt_base, row_off, ssrc);
  // 4) gemm1 second half || bucket build
  gemm1_mix<1><<<dim3(GEMM1B + NBKT), b256, 0, stream>>>(x, Wt_hi, Wt_lo, a1s, a1d, h1b, s1src, s1dst,
                                                         GEMM1B, GEMM1A, edges, bkt_cursor, pairs,
                                                         bkt_base, row_off, ssrc);
  // 5) layer 1 aggregation (bf16 value gather)
  agg1_kernel<<<dim3(NN / 4), b256, 0, stream>>>(row_off, ssrc, s1src, s1dst, (const __hip_bfloat16*)h1b, out1, NN);
  // 6) layer 2 GEMM with fused ELU + fused scores (single pass, BN=128)
  gemm2_fused<<<dim3((NN + 63) / 64), b256, 0, stream>>>(out1, W2, h2b, a2s, a2d, s1src, s1dst, NN);
  // 7) layer 2 aggregation over the 10k output indices only
  agg2_idx_kernel<<<dim3((NIDX * 64 + 255) / 256), b256, 0, stream>>>(row_off, ssrc, s1src, s1dst, h2b, indices, out, NIDX);
}